// Round 4
// baseline (281.639 us; speedup 1.0000x reference)
//
#include <hip/hip_runtime.h>

typedef _Float16 f16;
typedef _Float16 f16x8 __attribute__((ext_vector_type(8)));
typedef _Float16 f16x4 __attribute__((ext_vector_type(4)));
typedef float    f32x4 __attribute__((ext_vector_type(4)));
typedef unsigned int u32t;

#define AS1 __attribute__((address_space(1)))
#define AS3 __attribute__((address_space(3)))

static __device__ __forceinline__ void gload_lds16(const void* g, void* l) {
  __builtin_amdgcn_global_load_lds((const AS1 u32t*)g, (AS3 u32t*)l, 16, 0, 0);
}

static __device__ __forceinline__ f16x8 zero8() {
  f16x8 z;
#pragma unroll
  for (int j = 0; j < 8; ++j) z[j] = (f16)0;
  return z;
}

// ---------------- convert x (fp32 -> fp16) ----------------
__global__ void k_cvt_x(const float* __restrict__ in, f16* __restrict__ out, int n4) {
  int stride = gridDim.x * blockDim.x;
  for (int i = blockIdx.x * blockDim.x + threadIdx.x; i < n4; i += stride) {
    float4 v = ((const float4*)in)[i];
    f16x4 o;
    o[0] = (f16)v.x; o[1] = (f16)v.y; o[2] = (f16)v.z; o[3] = (f16)v.w;
    ((f16x4*)out)[i] = o;
  }
}

// ---------------- convert + transpose W: [1280][N] f32 -> [N][1280] f16 ----------------
__global__ void k_cvt_w_t(const float* __restrict__ W, f16* __restrict__ Wt, int N) {
  __shared__ float T[32][33];
  int bk = blockIdx.x % 40;          // 1280/32
  int bn = blockIdx.x / 40;
  int k0 = bk * 32, n0 = bn * 32;
  int r = threadIdx.x >> 5;          // 0..7
  int c = threadIdx.x & 31;
#pragma unroll
  for (int i = 0; i < 4; ++i)
    T[r + i * 8][c] = W[(size_t)(k0 + r + i * 8) * N + n0 + c];
  __syncthreads();
#pragma unroll
  for (int i = 0; i < 4; ++i)
    Wt[(size_t)(n0 + r + i * 8) * 1280 + k0 + c] = (f16)T[c][r + i * 8];
}

// ========== 256x256 GEMM, BK=64, 2-buffer, T3-minimum schedule ==========
// C[M=8192, NCOLS] = A[8192,1280] * Bt[NCOLS,1280]^T + bias
// 512 thr = 8 waves (2M x 4N); per-wave 128x64 (8 m x 4 n frags); 16x16x32 MFMA.
// LDS 128KB: buf = 32KB A + 32KB B, x2. Tile t -> buf t&1.
// Per tile: STAGE(t+1 -> buf^1) first (8 gloads fly across whole tile) ->
// 24 ds_read_b128 + 64 MFMA compiler-scheduled, NO intra-tile barriers/waits
// (per-wave lgkmcnt staggers waves; MFMA covers other waves' LDS reads) ->
// one __syncthreads() per tile (its vmcnt drain is ~free: loads had ~3000cy).
// Swizzle: phys_chunk = chunk ^ (row&7) on 128B rows (R2-verified, 0 conflicts);
// linear LDS dest + pre-swizzled global source column.

template<int NCOLS, bool F16OUT>
__global__ __launch_bounds__(512, 2)
void gemm_nt(const f16* __restrict__ A, const f16* __restrict__ Bt,
             const float* __restrict__ bias, void* __restrict__ Cout)
{
  __shared__ __align__(16) char lds[131072];
  const int tid = threadIdx.x;
  const int wave = tid >> 6, lane = tid & 63;
  const int rl = lane & 15, g = lane >> 4;
  const int wm = wave >> 2, wn = wave & 3;

  constexpr int NBN = NCOLS / 256;
  constexpr int NWG = 32 * NBN;
  const int bid = blockIdx.x;
  const int wgid = (bid & 7) * (NWG / 8) + (bid >> 3);   // XCD swizzle (NWG%8==0)
  const int bm = wgid / NBN, bn = wgid % NBN;
  const long row0 = (long)bm * 256, col0 = (long)bn * 256;

  // ---- staging: per-thread global src (pre-swizzled col), wave-uniform LDS dst ----
  // buf layout: A @ buf*65536, B @ buf*65536 + 32768. halves of 16KB each.
  const int srow = tid >> 3;                          // 0..63
  const int scol = ((tid & 7) ^ (srow & 7)) << 4;
  const char* gA = (const char*)A  + (row0 + srow) * 2560 + scol;
  const char* gB = (const char*)Bt + (col0 + srow) * 2560 + scol;
  char* const ldsw = lds + wave * 1024;

  auto STAGE4 = [&](int tk, int buf) {
    const long kb = (long)tk * 128;
#pragma unroll
    for (int half = 0; half < 2; ++half) {
      const char* sa = gA + half * (128 * 2560) + kb;
      char* da = ldsw + buf * 65536 + half * 16384;
      gload_lds16(sa, da);
      gload_lds16(sa + 64 * 2560, da + 8192);
      const char* sb = gB + half * (128 * 2560) + kb;
      char* db = ldsw + buf * 65536 + 32768 + half * 16384;
      gload_lds16(sb, db);
      gload_lds16(sb + 64 * 2560, db + 8192);
    }
  };

  // ---- fragment read offsets (swizzled) ----
  const int swz0 = ((0 + g) ^ (rl & 7)) << 4;         // kk=0 chunk
  const int swz1 = ((4 + g) ^ (rl & 7)) << 4;         // kk=1 chunk
  const int aoff = (wm * 128 + rl) << 7;
  const int boff = 32768 + ((wn * 64 + rl) << 7);

  auto LDA = [&](f16x8 (&af)[8], int buf, int mh) {
#pragma unroll
    for (int m = 0; m < 4; ++m) {
      const char* p = lds + buf * 65536 + aoff + (mh * 4 + m) * 2048;
      af[m * 2 + 0] = *(const f16x8*)(p + swz0);
      af[m * 2 + 1] = *(const f16x8*)(p + swz1);
    }
  };
  auto LDB = [&](f16x8 (&bf)[4], int buf, int nh) {
#pragma unroll
    for (int n = 0; n < 2; ++n) {
      const char* p = lds + buf * 65536 + boff + (nh * 2 + n) * 2048;
      bf[n * 2 + 0] = *(const f16x8*)(p + swz0);
      bf[n * 2 + 1] = *(const f16x8*)(p + swz1);
    }
  };

  f32x4 acc[8][4];
#pragma unroll
  for (int m = 0; m < 8; ++m)
#pragma unroll
    for (int n = 0; n < 4; ++n) acc[m][n] = (f32x4){0.f, 0.f, 0.f, 0.f};

  auto MM = [&](int mh, int nh, const f16x8 (&af)[8], const f16x8 (&bf)[4]) {
    __builtin_amdgcn_s_setprio(1);
#pragma unroll
    for (int m = 0; m < 4; ++m)
#pragma unroll
      for (int n = 0; n < 2; ++n)
#pragma unroll
        for (int kk = 0; kk < 2; ++kk)
          acc[mh * 4 + m][nh * 2 + n] = __builtin_amdgcn_mfma_f32_16x16x32_f16(
              af[m * 2 + kk], bf[n * 2 + kk], acc[mh * 4 + m][nh * 2 + n], 0, 0, 0);
    __builtin_amdgcn_s_setprio(0);
  };

  // One tile body: stage next tile first, then reads+MFMA (compiler-scheduled).
  auto TILEBODY = [&](int buf, int stk) {
    if (stk >= 0) STAGE4(stk, buf ^ 1);
    f16x8 afL[8], afH[8], bf0[4], bf1[4];
    LDA(afL, buf, 0);
    LDB(bf0, buf, 0);
    LDB(bf1, buf, 1);
    MM(0, 0, afL, bf0);
    MM(0, 1, afL, bf1);
    LDA(afH, buf, 1);
    MM(1, 1, afH, bf1);
    MM(1, 0, afH, bf0);
  };

  // prologue: stage tile0 -> buf0; barrier (drains vmcnt)
  STAGE4(0, 0);
  __syncthreads();

  // main loop: 20 K-tiles, 2 per iteration (compile-time buf indices)
#pragma unroll 1
  for (int tp = 0; tp < 10; ++tp) {
    TILEBODY(0, 2 * tp + 1);                    // even tile, stage odd tile
    __syncthreads();
    TILEBODY(1, tp < 9 ? 2 * tp + 2 : -1);      // odd tile, stage next even
    __syncthreads();
  }

  // ---- epilogue ----
#pragma unroll
  for (int m = 0; m < 8; ++m) {
#pragma unroll
    for (int n = 0; n < 4; ++n) {
      long c = col0 + wn * 64 + n * 16 + rl;
      float bv = bias[c];
#pragma unroll
      for (int r = 0; r < 4; ++r) {
        long rr = row0 + wm * 128 + m * 16 + g * 4 + r;
        float v = acc[m][n][r] + bv;
        if (F16OUT) ((f16*)Cout)[rr * NCOLS + c] = (f16)v;
        else        ((float*)Cout)[rr * NCOLS + c] = v;
      }
    }
  }
}

// ---------------- V transpose: qkv v-part -> vt[b*16+h][80][2048] ----------------
__global__ void k_vt(const f16* __restrict__ qkv, f16* __restrict__ vt) {
  __shared__ __align__(16) f16 T[128 * 136];
  int bid = blockIdx.x;              // 64 bh * 16 s-chunks
  int sc16 = bid & 15, bh = bid >> 4;
  int b = bh >> 4, h = bh & 15;
  int s0 = sc16 * 128;
  int t = threadIdx.x;
#pragma unroll
  for (int i = 0; i < 5; ++i) {
    int cid = i * 256 + t;           // 1280 = 128 s * 10 chunks
    int s = cid / 10, c = cid % 10;
    const f16* g = qkv + (size_t)((s0 + s) * 4 + b) * 3840 + 2560 + h * 80 + c * 8;
    f16x8 v = *(const f16x8*)g;
    int phys = c ^ ((s >> 3) & 7);
    *(f16x8*)(T + s * 136 + phys * 8) = v;
  }
  __syncthreads();
#pragma unroll
  for (int i = 0; i < 5; ++i) {
    int oid = i * 256 + t;           // 1280 = 80 hd * 16 s-subchunks
    int sc8 = oid & 15, hd = oid >> 4;
    f16x8 o;
#pragma unroll
    for (int j = 0; j < 8; ++j) {
      int row = sc8 * 8 + j;
      int phys = (hd >> 3) ^ (sc8 & 7);
      o[j] = T[row * 136 + phys * 8 + (hd & 7)];
    }
    *(f16x8*)(vt + (size_t)(bh * 80 + hd) * 2048 + s0 + sc8 * 8) = o;
  }
}

// ---------------- windowed attention ----------------
// block: (b, h, seg, qc) ; 512 threads = 8 waves * 16 queries
__global__ __launch_bounds__(512, 2)
void k_attn(const f16* __restrict__ qkv, const f16* __restrict__ vt,
            f16* __restrict__ ctx)
{
  __shared__ __align__(16) f16 sK[256 * 104];   // keys x (80 + zero-pad to 96, stride 104)
  __shared__ __align__(16) f16 sV[80 * 264];    // hd x 256 keys (stride 264)
  __shared__ __align__(16) f16 sP[128 * 72];    // q x 64-key chunk (stride 72)

  const int bid = blockIdx.x;                   // 1024
  const int qc = bid & 1, seg = (bid >> 1) & 7, h = (bid >> 4) & 15, b = bid >> 8;
  const int t = threadIdx.x;
  const int wave = t >> 6, lane = t & 63;
  const int s_key0 = seg * 256;

  // stage K (k-part of qkv, col base 1280 + h*80)
#pragma unroll
  for (int i = 0; i < 5; ++i) {
    int cid = i * 512 + t;                      // 2560 = 256 keys * 10 chunks
    int key = cid / 10, c = cid % 10;
    const f16* g = qkv + (size_t)((s_key0 + key) * 4 + b) * 3840 + 1280 + h * 80 + c * 8;
    *(f16x8*)(sK + key * 104 + c * 8) = *(const f16x8*)g;
  }
  { // zero cols 80..95
    int key = t >> 1, c = t & 1;
    *(f16x8*)(sK + key * 104 + 80 + c * 8) = zero8();
  }
  // stage V from vt
#pragma unroll
  for (int i = 0; i < 5; ++i) {
    int cid = i * 512 + t;                      // 2560 = 80 hd * 32 chunks
    int hd = cid >> 5, c = cid & 31;
    const f16* g = vt + (size_t)((b * 16 + h) * 80 + hd) * 2048 + s_key0 + c * 8;
    *(f16x8*)(sV + hd * 264 + c * 8) = *(const f16x8*)g;
  }

  // Q fragments direct from global (col base h*80); wave owns 16 queries
  const int q0 = s_key0 + qc * 128 + wave * 16;
  const int rl = lane & 15, g = lane >> 4;
  f16x8 qf[3];
  {
    const f16* gq = qkv + (size_t)((q0 + rl) * 4 + b) * 3840 + h * 80;
    qf[0] = *(const f16x8*)(gq + g * 8);
    qf[1] = *(const f16x8*)(gq + 32 + g * 8);
    if (g < 2) qf[2] = *(const f16x8*)(gq + 64 + g * 8);
    else       qf[2] = zero8();
  }
  __syncthreads();

  // QK^T : sc[nt] covers keys nt*16+(lane&15), rows g*4+r
  f32x4 sc[16];
#pragma unroll
  for (int nt = 0; nt < 16; ++nt) sc[nt] = (f32x4){0.f, 0.f, 0.f, 0.f};
#pragma unroll
  for (int nt = 0; nt < 16; ++nt) {
#pragma unroll
    for (int kk = 0; kk < 3; ++kk) {
      f16x8 bf = *(const f16x8*)(sK + (nt * 16 + rl) * 104 + kk * 32 + g * 8);
      sc[nt] = __builtin_amdgcn_mfma_f32_16x16x32_f16(qf[kk], bf, sc[nt], 0, 0, 0);
    }
  }

  // softmax (exact, full 256-key window in regs)
  const float scale = 0.11180339887498949f;
  float inv[4];
#pragma unroll
  for (int r = 0; r < 4; ++r) {
    float m = -1e30f;
#pragma unroll
    for (int nt = 0; nt < 16; ++nt) m = fmaxf(m, sc[nt][r]);
#pragma unroll
    for (int off = 8; off >= 1; off >>= 1) m = fmaxf(m, __shfl_xor(m, off));
    m *= scale;
    float sum = 0.f;
#pragma unroll
    for (int nt = 0; nt < 16; ++nt) {
      float p = __expf(sc[nt][r] * scale - m);
      sc[nt][r] = p;
      sum += p;
    }
#pragma unroll
    for (int off = 8; off >= 1; off >>= 1) sum += __shfl_xor(sum, off);
    inv[r] = 1.0f / sum;
  }

  // PV in 4 chunks of 64 keys; P bounced through WAVE-PRIVATE sP rows.
  // No block barriers needed: each wave reads only rows it wrote; the
  // compiler orders same-wave LDS write->read with lgkmcnt.
  f32x4 o[5];
#pragma unroll
  for (int nt = 0; nt < 5; ++nt) o[nt] = (f32x4){0.f, 0.f, 0.f, 0.f};
  const int prow0 = wave * 16;
  for (int ch = 0; ch < 4; ++ch) {
#pragma unroll
    for (int f = 0; f < 4; ++f) {
      int nt = ch * 4 + f;
#pragma unroll
      for (int r = 0; r < 4; ++r)
        sP[(prow0 + g * 4 + r) * 72 + f * 16 + rl] = (f16)sc[nt][r];
    }
#pragma unroll
    for (int kk = 0; kk < 2; ++kk) {
      f16x8 pa = *(const f16x8*)(sP + (prow0 + rl) * 72 + kk * 32 + g * 8);
#pragma unroll
      for (int nt = 0; nt < 5; ++nt) {
        f16x8 vb = *(const f16x8*)(sV + (nt * 16 + rl) * 264 + ch * 64 + kk * 32 + g * 8);
        o[nt] = __builtin_amdgcn_mfma_f32_16x16x32_f16(pa, vb, o[nt], 0, 0, 0);
      }
    }
  }

  // epilogue: normalize, store ctx fp16
#pragma unroll
  for (int nt = 0; nt < 5; ++nt) {
    int hd = nt * 16 + rl;
#pragma unroll
    for (int r = 0; r < 4; ++r) {
      long qrow = q0 + g * 4 + r;
      float v = o[nt][r] * inv[r];
      ctx[(qrow * 4 + b) * 1280 + h * 80 + hd] = (f16)v;
    }
  }
}

extern "C" void kernel_launch(void* const* d_in, const int* in_sizes, int n_in,
                              void* d_out, int out_size, void* d_ws, size_t ws_size,
                              hipStream_t stream)
{
  const float* x     = (const float*)d_in[0];
  const float* Wqkv  = (const float*)d_in[1];
  const float* bqkv  = (const float*)d_in[2];
  const float* Wproj = (const float*)d_in[3];
  const float* bproj = (const float*)d_in[4];

  char* ws = (char*)d_ws;
  f16* X16   = (f16*)(ws);                 // 20,971,520 B (reused as CTX16 after gemm1)
  f16* WQT   = (f16*)(ws + 20971520);      //  9,830,400 B
  f16* WPT   = (f16*)(ws + 30801920);      // 13,107,200 B
  f16* QKV16 = (f16*)(ws + 43909120);      // 62,914,560 B
  f16* VT    = (f16*)(ws + 106823680);     // 20,971,520 B  (total 127,795,200 B)
  f16* CTX16 = X16;                        // x dead after gemm1

  k_cvt_x<<<4096, 256, 0, stream>>>(x, X16, 8192 * 1280 / 4);
  k_cvt_w_t<<<40 * 120, 256, 0, stream>>>(Wqkv, WQT, 3840);
  k_cvt_w_t<<<40 * 160, 256, 0, stream>>>(Wproj, WPT, 5120);
  gemm_nt<3840, true ><<<480, 512, 0, stream>>>(X16, WQT, bqkv, QKV16);
  k_vt<<<1024, 256, 0, stream>>>(QKV16, VT);
  k_attn<<<1024, 512, 0, stream>>>(QKV16, VT, CTX16);
  gemm_nt<5120, false><<<640, 512, 0, stream>>>(CTX16, WPT, bproj, d_out);
}